// Round 4
// baseline (2253.655 us; speedup 1.0000x reference)
//
#include <hip/hip_runtime.h>

#define BB 8
#define CC 64
#define NN 4096
#define OO 128
#define KNN 20
#define NCH 8
#define JCH (NN / NCH)  // 512
#define TJ 64
#define PITCH 68        // 272 B rows: 16B-aligned for b128 broadcast reads

// ===========================================================================
// Top-20 as UNSORTED set with cached (kmax,kpos): accept = 20 parallel
// slot-selects + log-depth argmax tree. No serial 19-swap chain (R3 bubble
// latency ~180 cyc ran ~every j-step due to wave-any(insert) ~= 1).
// Set semantics identical to sorted-insert with strict '<' (lower-j wins at
// the boundary); final output is max-over-k => order-invariant.
// All state is NAMED SCALARS (R2 lesson: arrays don't SROA-promote).
// ===========================================================================
#define REP20(F, P) F(P,0) F(P,1) F(P,2) F(P,3) F(P,4) F(P,5) F(P,6) F(P,7) \
    F(P,8) F(P,9) F(P,10) F(P,11) F(P,12) F(P,13) F(P,14) F(P,15) F(P,16)   \
    F(P,17) F(P,18) F(P,19)

#define TS_DECL(P,k) float P##m##k = 1e30f; int P##p##k = -1;
#define TS_REPL(P,k)                                                        \
  { const bool _h = (P##kpos == (k));                                       \
    P##m##k = _h ? _d : P##m##k;                                            \
    P##p##k = _h ? _j : P##p##k; }

// assigns vd/xd = max of (va,xa),(vb,xb); '>' keeps left on ties
#define TS_N(vd, xd, va, xa, vb, xb)                                        \
  { const bool _g = (vb) > (va); vd = _g ? (vb) : (va); xd = _g ? (xb) : (xa); }

#define TS_TREE(P)                                                          \
  { float t0,t1,t2,t3,t4,t5,t6,t7,t8,t9; int y0,y1,y2,y3,y4,y5,y6,y7,y8,y9; \
    TS_N(t0,y0, P##m0,0,  P##m1,1)   TS_N(t1,y1, P##m2,2,  P##m3,3)         \
    TS_N(t2,y2, P##m4,4,  P##m5,5)   TS_N(t3,y3, P##m6,6,  P##m7,7)         \
    TS_N(t4,y4, P##m8,8,  P##m9,9)   TS_N(t5,y5, P##m10,10, P##m11,11)      \
    TS_N(t6,y6, P##m12,12, P##m13,13) TS_N(t7,y7, P##m14,14, P##m15,15)     \
    TS_N(t8,y8, P##m16,16, P##m17,17) TS_N(t9,y9, P##m18,18, P##m19,19)     \
    float u0,u1,u2,u3,u4; int z0,z1,z2,z3,z4;                               \
    TS_N(u0,z0, t0,y0, t1,y1) TS_N(u1,z1, t2,y2, t3,y3)                     \
    TS_N(u2,z2, t4,y4, t5,y5) TS_N(u3,z3, t6,y6, t7,y7)                     \
    TS_N(u4,z4, t8,y8, t9,y9)                                               \
    float w0,w1; int q0,q1;                                                 \
    TS_N(w0,q0, u0,z0, u1,z1) TS_N(w1,q1, u2,z2, u3,z3)                     \
    float e0; int r0;                                                       \
    TS_N(e0,r0, w0,q0, w1,q1)                                               \
    TS_N(P##kmax, P##kpos, e0,r0, u4,z4) }

#define TS_ACCEPT(P, dval, jval)                                            \
  if ((dval) < P##kmax) {                                                   \
    const float _d = (dval); const int _j = (jval);                         \
    REP20(TS_REPL, P)                                                       \
    TS_TREE(P)                                                              \
  }

// ---------------------------------------------------------------------------
// Kernel 1: per-point precompute (unchanged).
// ---------------------------------------------------------------------------
__global__ __launch_bounds__(256, 3) void precompute_kernel(
    const float* __restrict__ x, const float* __restrict__ W,
    const float* __restrict__ bias, float* __restrict__ A,
    float* __restrict__ Q, float* __restrict__ sqn) {
  const int b = blockIdx.y;
  const int n = blockIdx.x * 256 + threadIdx.x;
  const float* xb = x + (size_t)b * CC * NN;

  float xr[CC];
  float sq = 0.f;
#pragma unroll
  for (int c = 0; c < CC; ++c) {
    xr[c] = xb[(size_t)c * NN + n];
    sq = fmaf(xr[c], xr[c], sq);
  }
  sqn[(size_t)b * NN + n] = sq;

  float* Arow = A + ((size_t)b * NN + n) * OO;
  float* Qrow = Q + ((size_t)b * NN + n) * OO;

  for (int og = 0; og < OO; og += 4) {
    float p[4] = {0.f, 0.f, 0.f, 0.f};
    float g[4] = {0.f, 0.f, 0.f, 0.f};
#pragma unroll
    for (int oo = 0; oo < 4; ++oo) {
      const float* wr = W + (size_t)(og + oo) * (2 * CC);
#pragma unroll
      for (int c = 0; c < CC; c += 4) {
        float4 w1 = *(const float4*)(wr + c);
        float4 w2 = *(const float4*)(wr + CC + c);
        p[oo] = fmaf(w1.x, xr[c], p[oo]);
        p[oo] = fmaf(w1.y, xr[c + 1], p[oo]);
        p[oo] = fmaf(w1.z, xr[c + 2], p[oo]);
        p[oo] = fmaf(w1.w, xr[c + 3], p[oo]);
        g[oo] = fmaf(w2.x, xr[c], g[oo]);
        g[oo] = fmaf(w2.y, xr[c + 1], g[oo]);
        g[oo] = fmaf(w2.z, xr[c + 2], g[oo]);
        g[oo] = fmaf(w2.w, xr[c + 3], g[oo]);
      }
    }
    float4 pv = make_float4(p[0], p[1], p[2], p[3]);
    float4 qv = make_float4(g[0] - p[0] + bias[og + 0], g[1] - p[1] + bias[og + 1],
                            g[2] - p[2] + bias[og + 2], g[3] - p[3] + bias[og + 3]);
    *(float4*)(Arow + og) = pv;
    *(float4*)(Qrow + og) = qv;
  }
}

// ---------------------------------------------------------------------------
// Kernel 2: fused distance + per-chunk top-20, TWO i's per thread.
// Each broadcast ds_read_b128 of x_j now feeds 8 fma (4 per i-copy):
// LDS-pipe floor halves vs R3 (655 -> ~330 us). Grid = 8 x 8 x 8 = 512
// blocks = 2/CU (VGPR-limited) -> full residency in one round, no tail.
// ---------------------------------------------------------------------------
__global__ __launch_bounds__(256, 2) void knn_kernel(
    const float* __restrict__ x, const float* __restrict__ sqn,
    float* __restrict__ cd, int* __restrict__ ci) {
  __shared__ float xj[TJ * PITCH];
  __shared__ float xxj[TJ];

  const int b = blockIdx.z;
  const int ch = blockIdx.y;
  const int iA = blockIdx.x * 512 + threadIdx.x;  // copy A
  const int iB = iA + 256;                        // copy B
  const float* xb = x + (size_t)b * CC * NN;

  float xia[CC], xib[CC];
#pragma unroll
  for (int c = 0; c < CC; ++c) {
    xia[c] = xb[(size_t)c * NN + iA];
    xib[c] = xb[(size_t)c * NN + iB];
  }

  REP20(TS_DECL, A_)
  float A_kmax = 1e30f; int A_kpos = 0;
  REP20(TS_DECL, B_)
  float B_kmax = 1e30f; int B_kpos = 0;

  const int j0base = ch * JCH;
  for (int jt = 0; jt < JCH; jt += TJ) {
    const int j0 = j0base + jt;
    __syncthreads();
    for (int e = threadIdx.x; e < TJ * CC; e += 256) {
      const int jj = e & (TJ - 1);
      const int c = e >> 6;
      xj[jj * PITCH + c] = xb[(size_t)c * NN + j0 + jj];
    }
    if (threadIdx.x < TJ) xxj[threadIdx.x] = sqn[(size_t)b * NN + j0 + threadIdx.x];
    __syncthreads();

    for (int jj = 0; jj < TJ; ++jj) {
      const float* xp = xj + jj * PITCH;
      float aA0 = 0.f, aA1 = 0.f, aA2 = 0.f, aA3 = 0.f;
      float aB0 = 0.f, aB1 = 0.f, aB2 = 0.f, aB3 = 0.f;
#pragma unroll
      for (int c = 0; c < CC; c += 4) {
        float4 v = *(const float4*)(xp + c);  // broadcast b128, feeds 8 fma
        aA0 = fmaf(v.x, xia[c], aA0);
        aA1 = fmaf(v.y, xia[c + 1], aA1);
        aA2 = fmaf(v.z, xia[c + 2], aA2);
        aA3 = fmaf(v.w, xia[c + 3], aA3);
        aB0 = fmaf(v.x, xib[c], aB0);
        aB1 = fmaf(v.y, xib[c + 1], aB1);
        aB2 = fmaf(v.z, xib[c + 2], aB2);
        aB3 = fmaf(v.w, xib[c + 3], aB3);
      }
      const float xxv = xxj[jj];
      const float dA = fmaf(-2.f, (aA0 + aA1) + (aA2 + aA3), xxv);
      const float dB = fmaf(-2.f, (aB0 + aB1) + (aB2 + aB3), xxv);
      const int j = j0 + jj;
      TS_ACCEPT(A_, dA, j)
      TS_ACCEPT(B_, dB, j)
    }
  }

  // candidate lists are UNSORTED within a chunk (merge handles it)
  const size_t baseA = ((size_t)(b * NCH + ch) * KNN) * NN + iA;
  const size_t baseB = ((size_t)(b * NCH + ch) * KNN) * NN + iB;
#define TS_STA(P,k) cd[baseA + (size_t)(k) * NN] = P##m##k; \
                    ci[baseA + (size_t)(k) * NN] = P##p##k;
#define TS_STB(P,k) cd[baseB + (size_t)(k) * NN] = P##m##k; \
                    ci[baseB + (size_t)(k) * NN] = P##p##k;
  REP20(TS_STA, A_)
  REP20(TS_STB, B_)
#undef TS_STA
#undef TS_STB
}

// ---------------------------------------------------------------------------
// Kernel 3: merge 8 unsorted 20-lists -> final top-20 index set.
// Sorted-insert bubble (small kernel, 512 waves total). No early break:
// chunk lists are no longer sorted. Strict '<' keeps boundary semantics.
// ---------------------------------------------------------------------------
#define TK_LIST(OP) OP(0) OP(1) OP(2) OP(3) OP(4) OP(5) OP(6) OP(7) OP(8) \
    OP(9) OP(10) OP(11) OP(12) OP(13) OP(14) OP(15) OP(16) OP(17) OP(18) OP(19)
#define TK_DECL(k) float td##k = 1e30f; int ti##k = -1;
#define TK_SW(a, b)                                                        \
  {                                                                        \
    const bool _s = td##b < td##a;                                         \
    const float _fa = _s ? td##b : td##a;                                  \
    const float _fb = _s ? td##a : td##b;                                  \
    const int _ia = _s ? ti##b : ti##a;                                    \
    const int _ib = _s ? ti##a : ti##b;                                    \
    td##a = _fa; td##b = _fb; ti##a = _ia; ti##b = _ib;                    \
  }
#define TK_BUBBLE                                                          \
  TK_SW(18, 19) TK_SW(17, 18) TK_SW(16, 17) TK_SW(15, 16) TK_SW(14, 15)    \
  TK_SW(13, 14) TK_SW(12, 13) TK_SW(11, 12) TK_SW(10, 11) TK_SW(9, 10)     \
  TK_SW(8, 9) TK_SW(7, 8) TK_SW(6, 7) TK_SW(5, 6) TK_SW(4, 5)              \
  TK_SW(3, 4) TK_SW(2, 3) TK_SW(1, 2) TK_SW(0, 1)

__global__ __launch_bounds__(256, 3) void merge_kernel(
    const float* __restrict__ cd, const int* __restrict__ ci,
    int* __restrict__ idxf) {
  const int b = blockIdx.y;
  const int n = blockIdx.x * 256 + threadIdx.x;

  TK_LIST(TK_DECL)

  for (int ch = 0; ch < NCH; ++ch) {
    const size_t base = ((size_t)(b * NCH + ch) * KNN) * NN + n;
    for (int s = 0; s < KNN; ++s) {
      const float d = cd[base + (size_t)s * NN];
      if (d < td19) {
        const int j = ci[base + (size_t)s * NN];
        td19 = d;
        ti19 = j;
        TK_BUBBLE
      }
    }
  }

#define TK_STI(k) idxf[((size_t)b * KNN + (k)) * NN + n] = ti##k;
  TK_LIST(TK_STI)
#undef TK_STI
}

// ---------------------------------------------------------------------------
// Kernel 4: gather + max + leaky + transposed store (unchanged).
// ---------------------------------------------------------------------------
__global__ __launch_bounds__(128) void gather_kernel(
    const float* __restrict__ A, const float* __restrict__ Q,
    const int* __restrict__ idxf, float* __restrict__ out) {
  __shared__ int jidx[KNN][32];
  __shared__ float ob[32][OO + 1];

  const int b = blockIdx.y;
  const int n0 = blockIdx.x * 32;
  const int t = threadIdx.x;

  for (int e = t; e < KNN * 32; e += 128) {
    const int k = e >> 5, ii = e & 31;
    jidx[k][ii] = idxf[((size_t)b * KNN + k) * NN + n0 + ii];
  }
  __syncthreads();

  const float* Ab = A + (size_t)b * NN * OO;
  const float* Qb = Q + (size_t)b * NN * OO;

  for (int ii = 0; ii < 32; ++ii) {
    float m = -1e30f;
#pragma unroll
    for (int k = 0; k < KNN; ++k) {
      m = fmaxf(m, Ab[(size_t)jidx[k][ii] * OO + t]);
    }
    const float h = m + Qb[(size_t)(n0 + ii) * OO + t];
    ob[ii][t] = (h >= 0.f) ? h : 0.2f * h;
  }
  __syncthreads();

  float* ou = out + (size_t)b * OO * NN;
  for (int e = t; e < 32 * OO; e += 128) {
    const int ii = e & 31, oo = e >> 5;
    ou[(size_t)oo * NN + n0 + ii] = ob[ii][oo];
  }
}

// ---------------------------------------------------------------------------
extern "C" void kernel_launch(void* const* d_in, const int* in_sizes, int n_in,
                              void* d_out, int out_size, void* d_ws,
                              size_t ws_size, hipStream_t stream) {
  (void)in_sizes;
  (void)n_in;
  (void)out_size;
  (void)ws_size;
  const float* x = (const float*)d_in[0];
  const float* W = (const float*)d_in[1];
  const float* bias = (const float*)d_in[2];
  float* out = (float*)d_out;

  char* ws = (char*)d_ws;
  size_t off = 0;
  float* A = (float*)(ws + off);
  off += (size_t)BB * NN * OO * 4;
  float* Q = (float*)(ws + off);
  off += (size_t)BB * NN * OO * 4;
  float* sqn = (float*)(ws + off);
  off += (size_t)BB * NN * 4;
  float* cd = (float*)(ws + off);
  off += (size_t)BB * NCH * KNN * NN * 4;
  int* ci = (int*)(ws + off);
  off += (size_t)BB * NCH * KNN * NN * 4;
  int* idxf = (int*)(ws + off);
  off += (size_t)BB * KNN * NN * 4;

  precompute_kernel<<<dim3(NN / 256, BB), 256, 0, stream>>>(x, W, bias, A, Q, sqn);
  knn_kernel<<<dim3(NN / 512, NCH, BB), 256, 0, stream>>>(x, sqn, cd, ci);
  merge_kernel<<<dim3(NN / 256, BB), 256, 0, stream>>>(cd, ci, idxf);
  gather_kernel<<<dim3(NN / 32, BB), 128, 0, stream>>>(A, Q, idxf, out);
}

// Round 5
// 1068.422 us; speedup vs baseline: 2.1093x; 2.1093x over previous
//
#include <hip/hip_runtime.h>

#define BB 8
#define CC 64
#define NN 4096
#define OO 128
#define KNN 20
#define NCH 8
#define JCH (NN / NCH)  // 512
#define PITCH 68        // xT row: 64 x-floats + ||x||^2 + 3 pad (272 B)

// ===========================================================================
// Top-20 as UNSORTED set with cached (kmax,kpos) — verified R4 (absmax
// 0.015625). All state NAMED SCALARS (R2: arrays never SROA-promote).
// R4 lesson: allocator hard-caps ~128 VGPRs regardless of launch_bounds —
// keep per-thread live state ~<=110 (xi 64 + topk 40 + addr).
// ===========================================================================
#define REP20(F, P) F(P,0) F(P,1) F(P,2) F(P,3) F(P,4) F(P,5) F(P,6) F(P,7) \
    F(P,8) F(P,9) F(P,10) F(P,11) F(P,12) F(P,13) F(P,14) F(P,15) F(P,16)   \
    F(P,17) F(P,18) F(P,19)

#define TS_DECL(P,k) float P##m##k = 1e30f; int P##p##k = -1;
#define TS_REPL(P,k)                                                        \
  { const bool _h = (P##kpos == (k));                                       \
    P##m##k = _h ? _d : P##m##k;                                            \
    P##p##k = _h ? _j : P##p##k; }

#define TS_N(vd, xd, va, xa, vb, xb)                                        \
  { const bool _g = (vb) > (va); vd = _g ? (vb) : (va); xd = _g ? (xb) : (xa); }

#define TS_TREE(P)                                                          \
  { float t0,t1,t2,t3,t4,t5,t6,t7,t8,t9; int y0,y1,y2,y3,y4,y5,y6,y7,y8,y9; \
    TS_N(t0,y0, P##m0,0,  P##m1,1)   TS_N(t1,y1, P##m2,2,  P##m3,3)         \
    TS_N(t2,y2, P##m4,4,  P##m5,5)   TS_N(t3,y3, P##m6,6,  P##m7,7)         \
    TS_N(t4,y4, P##m8,8,  P##m9,9)   TS_N(t5,y5, P##m10,10, P##m11,11)      \
    TS_N(t6,y6, P##m12,12, P##m13,13) TS_N(t7,y7, P##m14,14, P##m15,15)     \
    TS_N(t8,y8, P##m16,16, P##m17,17) TS_N(t9,y9, P##m18,18, P##m19,19)     \
    float u0,u1,u2,u3,u4; int z0,z1,z2,z3,z4;                               \
    TS_N(u0,z0, t0,y0, t1,y1) TS_N(u1,z1, t2,y2, t3,y3)                     \
    TS_N(u2,z2, t4,y4, t5,y5) TS_N(u3,z3, t6,y6, t7,y7)                     \
    TS_N(u4,z4, t8,y8, t9,y9)                                               \
    float w0,w1; int q0,q1;                                                 \
    TS_N(w0,q0, u0,z0, u1,z1) TS_N(w1,q1, u2,z2, u3,z3)                     \
    float e0; int r0;                                                       \
    TS_N(e0,r0, w0,q0, w1,q1)                                               \
    TS_N(P##kmax, P##kpos, e0,r0, u4,z4) }

#define TS_ACCEPT(P, dval, jval)                                            \
  if ((dval) < P##kmax) {                                                   \
    const float _d = (dval); const int _j = (jval);                         \
    REP20(TS_REPL, P)                                                       \
    TS_TREE(P)                                                              \
  }

// ---------------------------------------------------------------------------
// Kernel 1: per-point precompute.
//   A[b][n][o]  = W1.x        Q[b][n][o] = W2.x - W1.x + bias
//   xT[b][n][.] = {x_n[0..63], ||x_n||^2, pad}  (wave-uniform rows for knn)
// ---------------------------------------------------------------------------
__global__ __launch_bounds__(256, 3) void precompute_kernel(
    const float* __restrict__ x, const float* __restrict__ W,
    const float* __restrict__ bias, float* __restrict__ A,
    float* __restrict__ Q, float* __restrict__ xT) {
  const int b = blockIdx.y;
  const int n = blockIdx.x * 256 + threadIdx.x;
  const float* xb = x + (size_t)b * CC * NN;

  float xr[CC];
  float sq = 0.f;
#pragma unroll
  for (int c = 0; c < CC; ++c) {
    xr[c] = xb[(size_t)c * NN + n];  // coalesced across threads
    sq = fmaf(xr[c], xr[c], sq);
  }

  float* xtr = xT + ((size_t)b * NN + n) * PITCH;
#pragma unroll
  for (int c = 0; c < CC; c += 4)
    *(float4*)(xtr + c) = make_float4(xr[c], xr[c + 1], xr[c + 2], xr[c + 3]);
  xtr[CC] = sq;

  float* Arow = A + ((size_t)b * NN + n) * OO;
  float* Qrow = Q + ((size_t)b * NN + n) * OO;

  for (int og = 0; og < OO; og += 4) {
    float p[4] = {0.f, 0.f, 0.f, 0.f};
    float g[4] = {0.f, 0.f, 0.f, 0.f};
#pragma unroll
    for (int oo = 0; oo < 4; ++oo) {
      const float* wr = W + (size_t)(og + oo) * (2 * CC);
#pragma unroll
      for (int c = 0; c < CC; c += 4) {
        float4 w1 = *(const float4*)(wr + c);
        float4 w2 = *(const float4*)(wr + CC + c);
        p[oo] = fmaf(w1.x, xr[c], p[oo]);
        p[oo] = fmaf(w1.y, xr[c + 1], p[oo]);
        p[oo] = fmaf(w1.z, xr[c + 2], p[oo]);
        p[oo] = fmaf(w1.w, xr[c + 3], p[oo]);
        g[oo] = fmaf(w2.x, xr[c], g[oo]);
        g[oo] = fmaf(w2.y, xr[c + 1], g[oo]);
        g[oo] = fmaf(w2.z, xr[c + 2], g[oo]);
        g[oo] = fmaf(w2.w, xr[c + 3], g[oo]);
      }
    }
    float4 pv = make_float4(p[0], p[1], p[2], p[3]);
    float4 qv = make_float4(g[0] - p[0] + bias[og + 0], g[1] - p[1] + bias[og + 1],
                            g[2] - p[2] + bias[og + 2], g[3] - p[3] + bias[og + 3]);
    *(float4*)(Arow + og) = pv;
    *(float4*)(Qrow + og) = qv;
  }
}

// ---------------------------------------------------------------------------
// Kernel 2: fused distance + per-chunk top-20, NO LDS.
// One i per thread (xi in VGPRs). x_j rows are read via WAVE-UNIFORM
// addresses from xT -> compiler scalarizes to s_load (SMEM pipe) or at
// worst same-address vector loads (one 16B L1 request each). This moves
// the j-broadcast off the per-CU LDS pipe (R3's 655 us structural floor).
// Same 4-partial fma arithmetic as R3/R4 -> bit-identical distances.
// ---------------------------------------------------------------------------
__global__ __launch_bounds__(256, 4) void knn_kernel(
    const float* __restrict__ x, const float* __restrict__ xT,
    float* __restrict__ cd, int* __restrict__ ci) {
  const int b = blockIdx.z;
  const int ch = blockIdx.y;
  const int i = blockIdx.x * 256 + threadIdx.x;
  const float* xb = x + (size_t)b * CC * NN;

  float xi[CC];
#pragma unroll
  for (int c = 0; c < CC; ++c) xi[c] = xb[(size_t)c * NN + i];

  REP20(TS_DECL, A_)
  float A_kmax = 1e30f; int A_kpos = 0;

  const float* rowbase = xT + (size_t)b * NN * PITCH;
  const int j0 = ch * JCH;
#pragma unroll 2
  for (int j = j0; j < j0 + JCH; ++j) {
    const float* row = rowbase + (size_t)j * PITCH;  // wave-uniform address
    float a0 = 0.f, a1 = 0.f, a2 = 0.f, a3 = 0.f;
#pragma unroll
    for (int c = 0; c < CC; c += 4) {
      const float4 v = *(const float4*)(row + c);  // uniform -> s_load_dwordx4
      a0 = fmaf(v.x, xi[c], a0);
      a1 = fmaf(v.y, xi[c + 1], a1);
      a2 = fmaf(v.z, xi[c + 2], a2);
      a3 = fmaf(v.w, xi[c + 3], a3);
    }
    const float d = fmaf(-2.f, (a0 + a1) + (a2 + a3), row[CC]);
    TS_ACCEPT(A_, d, j)
  }

  // candidate layout [b][ch][slot][i]; lists unsorted (merge handles it)
  const size_t base = ((size_t)(b * NCH + ch) * KNN) * NN + i;
#define TS_ST(P,k) cd[base + (size_t)(k) * NN] = P##m##k; \
                   ci[base + (size_t)(k) * NN] = P##p##k;
  REP20(TS_ST, A_)
#undef TS_ST
}

// ---------------------------------------------------------------------------
// Kernel 3: merge 8 unsorted 20-lists -> final top-20 index set.
// ---------------------------------------------------------------------------
#define TK_LIST(OP) OP(0) OP(1) OP(2) OP(3) OP(4) OP(5) OP(6) OP(7) OP(8) \
    OP(9) OP(10) OP(11) OP(12) OP(13) OP(14) OP(15) OP(16) OP(17) OP(18) OP(19)
#define TK_DECL(k) float td##k = 1e30f; int ti##k = -1;
#define TK_SW(a, b)                                                        \
  {                                                                        \
    const bool _s = td##b < td##a;                                         \
    const float _fa = _s ? td##b : td##a;                                  \
    const float _fb = _s ? td##a : td##b;                                  \
    const int _ia = _s ? ti##b : ti##a;                                    \
    const int _ib = _s ? ti##a : ti##b;                                    \
    td##a = _fa; td##b = _fb; ti##a = _ia; ti##b = _ib;                    \
  }
#define TK_BUBBLE                                                          \
  TK_SW(18, 19) TK_SW(17, 18) TK_SW(16, 17) TK_SW(15, 16) TK_SW(14, 15)    \
  TK_SW(13, 14) TK_SW(12, 13) TK_SW(11, 12) TK_SW(10, 11) TK_SW(9, 10)     \
  TK_SW(8, 9) TK_SW(7, 8) TK_SW(6, 7) TK_SW(5, 6) TK_SW(4, 5)              \
  TK_SW(3, 4) TK_SW(2, 3) TK_SW(1, 2) TK_SW(0, 1)

__global__ __launch_bounds__(256, 3) void merge_kernel(
    const float* __restrict__ cd, const int* __restrict__ ci,
    int* __restrict__ idxf) {
  const int b = blockIdx.y;
  const int n = blockIdx.x * 256 + threadIdx.x;

  TK_LIST(TK_DECL)

  for (int ch = 0; ch < NCH; ++ch) {
    const size_t base = ((size_t)(b * NCH + ch) * KNN) * NN + n;
    for (int s = 0; s < KNN; ++s) {
      const float d = cd[base + (size_t)s * NN];
      if (d < td19) {
        const int j = ci[base + (size_t)s * NN];
        td19 = d;
        ti19 = j;
        TK_BUBBLE
      }
    }
  }

#define TK_STI(k) idxf[((size_t)b * KNN + (k)) * NN + n] = ti##k;
  TK_LIST(TK_STI)
#undef TK_STI
}

// ---------------------------------------------------------------------------
// Kernel 4: gather + max + leaky + transposed store.
//   out[b][o][n] = leaky( Q[b][n][o] + max_k A[b][idx[n][k]][o] )
// ---------------------------------------------------------------------------
__global__ __launch_bounds__(128) void gather_kernel(
    const float* __restrict__ A, const float* __restrict__ Q,
    const int* __restrict__ idxf, float* __restrict__ out) {
  __shared__ int jidx[KNN][32];
  __shared__ float ob[32][OO + 1];

  const int b = blockIdx.y;
  const int n0 = blockIdx.x * 32;
  const int t = threadIdx.x;

  for (int e = t; e < KNN * 32; e += 128) {
    const int k = e >> 5, ii = e & 31;
    jidx[k][ii] = idxf[((size_t)b * KNN + k) * NN + n0 + ii];
  }
  __syncthreads();

  const float* Ab = A + (size_t)b * NN * OO;
  const float* Qb = Q + (size_t)b * NN * OO;

  for (int ii = 0; ii < 32; ++ii) {
    float m = -1e30f;
#pragma unroll
    for (int k = 0; k < KNN; ++k) {
      m = fmaxf(m, Ab[(size_t)jidx[k][ii] * OO + t]);
    }
    const float h = m + Qb[(size_t)(n0 + ii) * OO + t];
    ob[ii][t] = (h >= 0.f) ? h : 0.2f * h;
  }
  __syncthreads();

  float* ou = out + (size_t)b * OO * NN;
  for (int e = t; e < 32 * OO; e += 128) {
    const int ii = e & 31, oo = e >> 5;
    ou[(size_t)oo * NN + n0 + ii] = ob[ii][oo];
  }
}

// ---------------------------------------------------------------------------
extern "C" void kernel_launch(void* const* d_in, const int* in_sizes, int n_in,
                              void* d_out, int out_size, void* d_ws,
                              size_t ws_size, hipStream_t stream) {
  (void)in_sizes;
  (void)n_in;
  (void)out_size;
  (void)ws_size;
  const float* x = (const float*)d_in[0];
  const float* W = (const float*)d_in[1];
  const float* bias = (const float*)d_in[2];
  float* out = (float*)d_out;

  char* ws = (char*)d_ws;
  size_t off = 0;
  float* A = (float*)(ws + off);
  off += (size_t)BB * NN * OO * 4;            // 16 MB
  float* Q = (float*)(ws + off);
  off += (size_t)BB * NN * OO * 4;            // 16 MB
  float* xT = (float*)(ws + off);
  off += (size_t)BB * NN * PITCH * 4;         // 8.9 MB
  float* cd = (float*)(ws + off);
  off += (size_t)BB * NCH * KNN * NN * 4;     // 21 MB
  int* ci = (int*)(ws + off);
  off += (size_t)BB * NCH * KNN * NN * 4;     // 21 MB
  int* idxf = (int*)(ws + off);
  off += (size_t)BB * KNN * NN * 4;           // 2.6 MB

  precompute_kernel<<<dim3(NN / 256, BB), 256, 0, stream>>>(x, W, bias, A, Q, xT);
  knn_kernel<<<dim3(NN / 256, NCH, BB), 256, 0, stream>>>(x, xT, cd, ci);
  merge_kernel<<<dim3(NN / 256, BB), 256, 0, stream>>>(cd, ci, idxf);
  gather_kernel<<<dim3(NN / 32, BB), 128, 0, stream>>>(A, Q, idxf, out);
}